// Round 1
// 98.019 us; speedup vs baseline: 1.0073x; 1.0073x over previous
//
#include <hip/hip_runtime.h>

// BilinearFullSymLoss: B=32 samples, grid [B,2,512,512] fp32.
// Per sample: masked sum of (delta0*sy + delta1*sx)^2 / count, then mean over B.
// Mask excludes the jnp.roll wrap region -> plain offset loads, no wrapping.
// neg branch simplified: d_neg = fx*a2 + (1-fx)*a1 - fy*s_top - (1-fy)*s_bot.
//
// Round 5 (this session):
//  - branch-free row loop: clamped row index + row mask instead of wave `break`
//    (masked rows contribute exactly +0.0 -> bitwise-identical accumulation
//    order; clamp keeps every address in-bounds). Lets the compiler keep all
//    strip loads in flight instead of a serialized load->waitcnt->compute
//    chain per row.
//  - explicit next-row prefetch (load r+1 before computing r).
//  - XCD-chunked block remap (1024 blocks, 1024%8==0 -> bijective): each XCD
//    owns 128 consecutive strips = 4 whole samples, so the dy1-row strip
//    overlap and the anchor/center same-row reuse hit that XCD's L2 instead
//    of being re-fetched from HBM.

#define GH 512
#define GW 512
#define GB 32
#define CH (GH * GW)
#define RPB 16
#define BLOCK 256
#define NBLK_X (GH / RPB)        // 32
#define NPART (NBLK_X * GB)      // 1024

struct F4U { float x, y, z, w; };   // align 4 -> dword-aligned 16B loads ok

__device__ __forceinline__ void load9(const float* __restrict__ p, float* o) {
    const F4U a = *(const F4U*)p;
    const F4U b = *(const F4U*)(p + 4);
    o[0]=a.x; o[1]=a.y; o[2]=a.z; o[3]=a.w;
    o[4]=b.x; o[5]=b.y; o[6]=b.z; o[7]=b.w;
    o[8] = p[8];
}

__device__ __forceinline__ void load8(const float* __restrict__ p, float* o) {
    const F4U a = *(const F4U*)p;
    const F4U b = *(const F4U*)(p + 4);
    o[0]=a.x; o[1]=a.y; o[2]=a.z; o[3]=a.w;
    o[4]=b.x; o[5]=b.y; o[6]=b.z; o[7]=b.w;
}

__global__ __launch_bounds__(BLOCK) void bilinear_sym_loss_stage1(
    const float* __restrict__ grid,
    const float* __restrict__ gt,   // [B,2]  (gt_x, gt_y)
    const float* __restrict__ gd,   // [B,2]  (sx, sy)
    float* __restrict__ partials)
{
    // XCD-chunked remap: hardware round-robins consecutive flat block ids
    // across the 8 XCDs; give each XCD a contiguous chunk of logical ids.
    const int flat = blockIdx.y * NBLK_X + blockIdx.x;
    const int logi = (flat & 7) * (NPART >> 3) + (flat >> 3);   // bijective
    const int b  = logi >> 5;             // sample     (logi / NBLK_X)
    const int bx = logi & (NBLK_X - 1);   // row strip  (logi % NBLK_X)

    const float dx = -10.0f * gt[b * 2 + 0];
    const float dy =  10.0f * gt[b * 2 + 1];
    const float sx = gd[b * 2 + 0];
    const float sy = gd[b * 2 + 1];

    const float dy1f = floorf(dy);
    const float dx1f = floorf(dx);
    const int dy1 = (int)dy1f;
    const int dx1 = (int)dx1f;
    const float fy = dy - dy1f;
    const float fx = dx - dx1f;

    const bool pos = dx > 0.0f;
    const int rows = GH - dy1 - 1;                        // 506..511
    const int cols = pos ? (GW - dx1 - 1) : (GW + dx1);   // 507..509

    const float omfx = 1.0f - fx;
    const float omfy = 1.0f - fy;
    const float w22 = fx * fy;
    const float w21 = fx * omfy;
    const float w12 = omfx * fy;
    const float w11 = omfx * omfy;

    const float* __restrict__ g0 = grid + (size_t)b * 2u * CH;

    const int tid = threadIdx.x;
    const int cc = tid & 63;          // column chunk (8 cols each)
    const int rg = tid >> 6;          // row group (wave-uniform)
    const int i0 = bx * RPB + rg * 4;
    const int rc = rows - 1;          // clamp target for masked rows

    // Last chunk re-anchors at cols-8; kmin masks elements already counted
    // by the previous chunk. All lanes then run identical vector code.
    int j0 = cc << 3;
    int kmin = 0;
    if (j0 > cols - 8) { kmin = j0 - (cols - 8); j0 = cols - 8; }

    float acc = 0.0f;

    if (pos) {
        const float* baseA = g0 + dx1 + j0;   // anchor rows, col base
        const float* baseC = g0 + j0;         // center rows, col base
        float P0[9], P1[9];
        {
            const int ip = min(i0, rc) + dy1;
            load9(baseA + ip * GW, P0);
            load9(baseA + ip * GW + CH, P1);
        }
        float B0[9], B1[9], C0[8], C1[8];
        {
            const int ic = min(i0, rc);
            load9(baseA + (ic + dy1 + 1) * GW, B0);
            load9(baseA + (ic + dy1 + 1) * GW + CH, B1);
            load8(baseC + ic * GW, C0);
            load8(baseC + ic * GW + CH, C1);
        }
        #pragma unroll
        for (int r = 0; r < 4; ++r) {
            float N0[9], N1[9], D0[8], D1[8];
            if (r < 3) {   // compile-time under unroll
                const int ic = min(i0 + r + 1, rc);
                load9(baseA + (ic + dy1 + 1) * GW, N0);
                load9(baseA + (ic + dy1 + 1) * GW + CH, N1);
                load8(baseC + ic * GW, D0);
                load8(baseC + ic * GW + CH, D1);
            }
            const bool rowok = (i0 + r) < rows;   // wave-uniform
            #pragma unroll
            for (int k = 0; k < 8; ++k) {
                float t0 = w11 * P0[k];
                t0 = fmaf(w21, P0[k + 1], t0);
                t0 = fmaf(w12, B0[k], t0);
                t0 = fmaf(w22, B0[k + 1], t0);
                const float d0 = C0[k] - t0;
                float t1 = w11 * P1[k];
                t1 = fmaf(w21, P1[k + 1], t1);
                t1 = fmaf(w12, B1[k], t1);
                t1 = fmaf(w22, B1[k + 1], t1);
                const float d1 = C1[k] - t1;
                float v = fmaf(d0, sy, d1 * sx);
                v = (rowok && k >= kmin) ? v : 0.0f;
                acc = fmaf(v, v, acc);    // masked: +0.0, order preserved
            }
            #pragma unroll
            for (int k = 0; k < 9; ++k) { P0[k] = B0[k]; P1[k] = B1[k]; }
            if (r < 3) {
                #pragma unroll
                for (int k = 0; k < 9; ++k) { B0[k] = N0[k]; B1[k] = N1[k]; }
                #pragma unroll
                for (int k = 0; k < 8; ++k) { C0[k] = D0[k]; C1[k] = D1[k]; }
            }
        }
    } else {
        const int jo = -dx1;   // 3..5
        const float* baseT = g0 + jo + j0;    // sampled rows (s_top/s_bot)
        const float* baseA = g0 + j0;         // anchor rows
        float T0[8], T1[8];
        {
            const int it = min(i0, rc);
            load8(baseT + it * GW, T0);
            load8(baseT + it * GW + CH, T1);
        }
        float S0[8], S1[8], A0[9], A1[9];
        {
            const int ic = min(i0, rc);
            load8(baseT + (ic + 1) * GW, S0);
            load8(baseT + (ic + 1) * GW + CH, S1);
            load9(baseA + (ic + dy1 + 1) * GW, A0);
            load9(baseA + (ic + dy1 + 1) * GW + CH, A1);
        }
        #pragma unroll
        for (int r = 0; r < 4; ++r) {
            float NS0[8], NS1[8], NA0[9], NA1[9];
            if (r < 3) {
                const int ic = min(i0 + r + 1, rc);
                load8(baseT + (ic + 1) * GW, NS0);
                load8(baseT + (ic + 1) * GW + CH, NS1);
                load9(baseA + (ic + dy1 + 1) * GW, NA0);
                load9(baseA + (ic + dy1 + 1) * GW + CH, NA1);
            }
            const bool rowok = (i0 + r) < rows;
            #pragma unroll
            for (int k = 0; k < 8; ++k) {
                float d0 = fx * A0[k + 1];
                d0 = fmaf(omfx, A0[k], d0);
                d0 = fmaf(-fy, T0[k], d0);
                d0 = fmaf(-omfy, S0[k], d0);
                float d1 = fx * A1[k + 1];
                d1 = fmaf(omfx, A1[k], d1);
                d1 = fmaf(-fy, T1[k], d1);
                d1 = fmaf(-omfy, S1[k], d1);
                float v = fmaf(d0, sy, d1 * sx);
                v = (rowok && k >= kmin) ? v : 0.0f;
                acc = fmaf(v, v, acc);
            }
            #pragma unroll
            for (int k = 0; k < 8; ++k) { T0[k] = S0[k]; T1[k] = S1[k]; }
            if (r < 3) {
                #pragma unroll
                for (int k = 0; k < 8; ++k) { S0[k] = NS0[k]; S1[k] = NS1[k]; }
                #pragma unroll
                for (int k = 0; k < 9; ++k) { A0[k] = NA0[k]; A1[k] = NA1[k]; }
            }
        }
    }

    // Block reduction: wave64 shuffle, then LDS across the 4 waves.
    for (int off = 32; off > 0; off >>= 1)
        acc += __shfl_down(acc, off, 64);

    __shared__ float wave_sums[BLOCK / 64];
    const int lane = tid & 63;
    const int wid = tid >> 6;
    if (lane == 0) wave_sums[wid] = acc;
    __syncthreads();

    if (tid == 0) {
        const float s = wave_sums[0] + wave_sums[1] + wave_sums[2] + wave_sums[3];
        const float count = (float)rows * (float)cols;
        const float scale = 1.0f / (count * (float)GB);
        partials[b * NBLK_X + bx] = s * scale;   // covers ws poison (bijective remap)
    }
}

__global__ __launch_bounds__(BLOCK) void bilinear_sym_loss_stage2(
    const float* __restrict__ partials,
    float* __restrict__ out)
{
    const int tid = threadIdx.x;
    float acc = 0.0f;
    for (int i = tid; i < NPART; i += BLOCK)
        acc += partials[i];

    for (int off = 32; off > 0; off >>= 1)
        acc += __shfl_down(acc, off, 64);

    __shared__ float wave_sums[BLOCK / 64];
    const int lane = tid & 63;
    const int wid = tid >> 6;
    if (lane == 0) wave_sums[wid] = acc;
    __syncthreads();

    if (tid == 0)
        out[0] = wave_sums[0] + wave_sums[1] + wave_sums[2] + wave_sums[3];
}

extern "C" void kernel_launch(void* const* d_in, const int* in_sizes, int n_in,
                              void* d_out, int out_size, void* d_ws, size_t ws_size,
                              hipStream_t stream) {
    const float* grid = (const float*)d_in[0];
    const float* gt   = (const float*)d_in[1];
    const float* gd   = (const float*)d_in[2];
    float* out = (float*)d_out;
    float* partials = (float*)d_ws;  // NPART floats = 4 KiB

    dim3 grid1(NBLK_X, GB);
    bilinear_sym_loss_stage1<<<grid1, dim3(BLOCK), 0, stream>>>(grid, gt, gd, partials);
    bilinear_sym_loss_stage2<<<dim3(1), dim3(BLOCK), 0, stream>>>(partials, out);
}